// Round 1
// 225.497 us; speedup vs baseline: 1.0665x; 1.0665x over previous
//
#include <hip/hip_runtime.h>
#include <cstdint>
#include <cstddef>

// Problem constants (match reference setup_inputs)
#define BB 32
#define SS 4096          // 2^12
#define FEAT_ 64
#define HID_ 32
#define NN 1024          // MAX_NODES
#define RPB 8            // adjacency rows per block (dense LDS tile = 32 KB)

#define EDGE_BLOCKS ((BB * SS) / 256)   // 512 edge-MLP blocks
#define NF_BLOCKS   ((BB * NN) / 32)    // 1024 node-feature blocks (32 rows each)

typedef int v4i __attribute__((ext_vector_type(4)));

// ---------------------------------------------------------------------------
// Kernel 0: factor the edge MLP. h = relu([e_s;e_d]@W1 + b1) is linear before
// the ReLU, so precompute per-node partials once:
//   AB[n][0:32]  = emb[n] @ W1[0:64]   + b1   (the "A"/src half)
//   AB[n][32:64] = emb[n] @ W1[64:128]        (the "B"/dst half)
// 8.4M FMA total vs 537M in the per-edge formulation. Table = 256 KB,
// L2-resident for the edge phase.
// ---------------------------------------------------------------------------
__global__ void ab_kernel(const float* __restrict__ emb,
                          const float* __restrict__ W1,
                          const float* __restrict__ b1,
                          float* __restrict__ ab) {
    int idx = blockIdx.x * 256 + threadIdx.x;   // 0 .. 65535
    int n = idx >> 6;                           // node
    int c = idx & 63;                           // half*32 + j
    int half = c >> 5, j = c & 31;
    const float* e = emb + (n << 6);            // wave-uniform row (64 lanes share n)
    const float* w = W1 + (half << 11) + j;     // W1[(half*64 + k)*32 + j]
    float acc = half ? 0.0f : b1[j];            // fold b1 into the A half once
    #pragma unroll
    for (int k = 0; k < 64; ++k)
        acc = fmaf(e[k], w[k << 5], acc);
    ab[idx] = acc;
}

// ---------------------------------------------------------------------------
// Kernel 1 (grid-fused): blocks [0,512) = per-edge combine -> w[b,s];
// blocks [512,1536) = node_features gather + fused L2-normalize.
//
// Edge part: per edge only 32 add+relu+fma and two 128 B gathers from the
// L2-resident AB table (was: 4096 FMA + 4096 W1 loads per edge).
//
// NF part: 8 rows per wave (was 4) -> half the LDS-read/loop iterations for
// the same compare count; dst staging traffic 33.5 -> 16.7 MB. Row sums
// accumulate in-register in s-order (deterministic), butterfly L2-normalize,
// non-temporal row writes.
// ---------------------------------------------------------------------------
__global__ void nf_edge_kernel(const float* __restrict__ flow,
                               const int* __restrict__ src,
                               const int* __restrict__ dst,
                               const float* __restrict__ vol,
                               const float* __restrict__ ab,
                               const float* __restrict__ W2,
                               const float* __restrict__ b2,
                               float* __restrict__ nf,
                               float* __restrict__ wout) {
    if (blockIdx.x < EDGE_BLOCKS) {
        int i = blockIdx.x * 256 + threadIdx.x;       // b*S + s
        int si = src[i], di = dst[i];
        const float4* As = (const float4*)(ab + (si << 6));         // A[src] (+b1)
        const float4* Bd = (const float4*)(ab + (di << 6) + HID_);  // B[dst]
        float dotv = b2[0];
        #pragma unroll
        for (int q = 0; q < 8; ++q) {
            float4 a  = As[q];
            float4 bv = Bd[q];
            float4 wv = *(const float4*)(W2 + (q << 2));
            dotv += fmaxf(a.x + bv.x, 0.0f) * wv.x;
            dotv += fmaxf(a.y + bv.y, 0.0f) * wv.y;
            dotv += fmaxf(a.z + bv.z, 0.0f) * wv.z;
            dotv += fmaxf(a.w + bv.w, 0.0f) * wv.w;
        }
        float edge_w = 1.0f / (1.0f + expf(-dotv));
        float vol_w  = 1.0f / (1.0f + expf(-vol[i] / 1000.0f));
        wout[i] = edge_w * vol_w;
        return;
    }

    // ---- node-features part ----
    int nb = blockIdx.x - EDGE_BLOCKS;       // 0..1023
    int row0 = nb << 5;                      // 32 rows per block; global row = b*NN+node
    int b = row0 >> 10;
    __shared__ int sdst[SS];

    const int4* g = (const int4*)(dst + (size_t)b * SS);
    int4* sd4 = (int4*)sdst;
    for (int t = threadIdx.x; t < SS / 4; t += 256) sd4[t] = g[t];
    __syncthreads();

    int wave = threadIdx.x >> 6;
    int lane = threadIdx.x & 63;
    int r0 = row0 + (wave << 3);             // this wave's first of 8 rows
    int node0 = r0 & (NN - 1);
    const float* fb = flow + ((size_t)b * SS << 6);

    float acc[8] = {0.f, 0.f, 0.f, 0.f, 0.f, 0.f, 0.f, 0.f};
    for (int s0 = 0; s0 < SS; s0 += 64) {
        int d = sdst[s0 + lane];
        #pragma unroll
        for (int j = 0; j < 8; ++j) {
            unsigned long long m = __ballot(d == node0 + j);
            while (m) {                      // ~4 hits per row over the whole scan
                int bit = __ffsll((long long)m) - 1;
                m &= m - 1;
                acc[j] += fb[((s0 + bit) << 6) + lane];  // coalesced 256 B row
            }
        }
    }

    #pragma unroll
    for (int j = 0; j < 8; ++j) {
        float ss = acc[j] * acc[j];
        #pragma unroll
        for (int off = 32; off > 0; off >>= 1) ss += __shfl_xor(ss, off, 64);
        float v = acc[j] / fmaxf(sqrtf(ss), 1e-12f);
        __builtin_nontemporal_store(v, &nf[((size_t)(r0 + j) << 6) + lane]);
    }
}

// ---------------------------------------------------------------------------
// Kernel 2: adjacency via dense LDS priority tile (unchanged — at its write
// roofline, ~128 MB nt-stream). Block owns RPB=8 rows of one batch:
//   phase 0: zero D; phase 1: atomicMax prio (s+1 / S+s+1, disjoint ranges ->
//   max == last-write-wins); phase 2: unique winner deposits w bits;
//   phase 3: stream out as non-temporal float4.
// ---------------------------------------------------------------------------
__global__ void adj_dense_kernel(const int* __restrict__ src,
                                 const int* __restrict__ dst,
                                 const float* __restrict__ wbuf,
                                 float* __restrict__ adj) {
    int b  = blockIdx.x >> 7;                 // 128 blocks per batch
    int r0 = (blockIdx.x & 127) << 3;         // first of RPB rows
    int tid = threadIdx.x;

    __shared__ int D[RPB * NN];               // 32 KB dense tile

    const int* sb = src + (size_t)b * SS;
    const int* db = dst + (size_t)b * SS;
    int svr[16], dvr[16];
    #pragma unroll
    for (int i = 0; i < 16; ++i) {
        svr[i] = sb[tid + (i << 8)];
        dvr[i] = db[tid + (i << 8)];
    }

    int4* D4 = (int4*)D;
    int4 z; z.x = z.y = z.z = z.w = 0;
    #pragma unroll
    for (int i = 0; i < RPB * NN / 4 / 256; ++i) D4[tid + i * 256] = z;
    __syncthreads();

    #pragma unroll
    for (int i = 0; i < 16; ++i) {
        int s = tid + (i << 8);
        unsigned lr1 = (unsigned)(svr[i] - r0);
        if (lr1 < RPB) atomicMax(&D[(lr1 << 10) + dvr[i]], s + 1);
        unsigned lr2 = (unsigned)(dvr[i] - r0);
        if (lr2 < RPB) atomicMax(&D[(lr2 << 10) + svr[i]], SS + s + 1);
    }
    __syncthreads();

    const float* wb = wbuf + (size_t)b * SS;
    #pragma unroll
    for (int i = 0; i < 16; ++i) {
        int s = tid + (i << 8);
        unsigned lr1 = (unsigned)(svr[i] - r0);
        unsigned lr2 = (unsigned)(dvr[i] - r0);
        if ((lr1 < RPB) | (lr2 < RPB)) {
            int wbits = __float_as_int(wb[s]);
            if (lr1 < RPB && D[(lr1 << 10) + dvr[i]] == s + 1)
                D[(lr1 << 10) + dvr[i]] = wbits;
            if (lr2 < RPB && D[(lr2 << 10) + svr[i]] == SS + s + 1)
                D[(lr2 << 10) + svr[i]] = wbits;
        }
    }
    __syncthreads();

    const v4i* Df = (const v4i*)D;
    v4i* out = (v4i*)(adj + ((size_t)b * NN + r0) * NN);
    #pragma unroll
    for (int i = 0; i < RPB * NN / 4 / 256; ++i)
        __builtin_nontemporal_store(Df[tid + i * 256], &out[tid + i * 256]);
}

extern "C" void kernel_launch(void* const* d_in, const int* in_sizes, int n_in,
                              void* d_out, int out_size, void* d_ws, size_t ws_size,
                              hipStream_t stream) {
    const float* flow = (const float*)d_in[0];   // (B,S,64)
    const int*   src  = (const int*)d_in[1];     // (B,S)
    const int*   dst  = (const int*)d_in[2];     // (B,S)
    const float* vol  = (const float*)d_in[3];   // (B,S)
    const float* emb  = (const float*)d_in[4];   // (1024,64)
    const float* W1   = (const float*)d_in[5];   // (128,32)
    const float* b1   = (const float*)d_in[6];   // (32,)
    const float* W2   = (const float*)d_in[7];   // (32,1)
    const float* b2   = (const float*)d_in[8];   // (1,)

    float* nf   = (float*)d_out;                        // (B,N,64)
    float* adj  = nf + (size_t)BB * NN * FEAT_;         // (B,N,N)
    float* wbuf = (float*)d_ws;                         // (B,S) edge weights

    // 256 KB AB table: prefer workspace after wbuf; else borrow the tail of
    // the adjacency output (ab_kernel+nf_edge_kernel complete before
    // adj_dense_kernel overwrites every adjacency byte, same stream).
    float* ab;
    if (ws_size >= (size_t)(BB * SS + NN * 64) * sizeof(float))
        ab = wbuf + (size_t)BB * SS;
    else
        ab = adj + (size_t)BB * NN * NN - (size_t)NN * 64;

    // Every output byte is written exactly once by the kernels below —
    // no memset of d_out at all.
    ab_kernel<<<(NN * 64) / 256, 256, 0, stream>>>(emb, W1, b1, ab);
    nf_edge_kernel<<<EDGE_BLOCKS + NF_BLOCKS, 256, 0, stream>>>(
        flow, src, dst, vol, ab, W2, b2, nf, wbuf);
    adj_dense_kernel<<<BB * (NN / RPB), 256, 0, stream>>>(src, dst, wbuf, adj);
}